// Round 7
// baseline (6891.545 us; speedup 1.0000x reference)
//
#include <hip/hip_runtime.h>
#include <hip/hip_fp16.h>
#include <math.h>

#define NB   16    // batch
#define TE   256   // T_ENC
#define TD   200   // T_DEC
#define EE   512   // encoder dim
#define ATT  128
#define PREN 256
#define HH   1024
#define NMEL 80
#define NLOC 32
#define KWW  31
#define PADW 15

// workspace offsets (in floats)
#define OFF_X2   0                        // [TD][NB][PREN]
#define OFF_PE   (OFF_X2 + TD*NB*PREN)    // [NB][TE][ATT]
#define OFF_AWC  (OFF_PE + NB*TE*ATT)     // [NB][TE]
#define OFF_ENR  (OFF_AWC + NB*TE)        // [NB][16][6]  f4 recs: 3 f32 + tag(.w)
#define OFF_QVR  (OFF_ENR + NB*16*6*4)    // [NB][16][2]  f4 recs: 4 fp16 + tag(.z)
#define OFF_CTR  (OFF_QVR + NB*16*2*4)    // [NB][176]    f4 recs: 3 f32 + tag(.w)
#define OFF_H1R  (OFF_CTR + NB*176*4)     // [NB][256]    f4 recs: 4 fp16 + tag(.z)
#define OFF_H2R  (OFF_H1R + NB*256*4)     // [NB][256]    f4 recs: 4 fp16 + tag(.z)
#define OFF_END  (OFF_H2R + NB*256*4)

// dynamic LDS: lw0x 12x64 f4 | lw0c 12x177 f4 (3-packed ctx cols, tag-slot=0) | lw1 12x256 f4
#define LW0X_F4  (12*64)
#define LW0C_F4  (12*177)
#define LW1_F4   (12*256)
#define DYN_BYTES ((LW0X_F4 + LW0C_F4 + LW1_F4) * 16)

typedef float f4 __attribute__((ext_vector_type(4)));

__device__ __forceinline__ float sigmf(float x) { return 1.0f / (1.0f + expf(-x)); }
__device__ __forceinline__ float dot4(f4 a, f4 b) {
  return a.x*b.x + a.y*b.y + a.z*b.z + a.w*b.w;
}
__device__ __forceinline__ float red32(float v) {
  v += __shfl_down(v, 16, 32); v += __shfl_down(v, 8, 32);
  v += __shfl_down(v, 4, 32);  v += __shfl_down(v, 2, 32);
  v += __shfl_down(v, 1, 32);
  return v;
}
__device__ __forceinline__ float red64(float v) {
  v += __shfl_down(v, 32); v += __shfl_down(v, 16); v += __shfl_down(v, 8);
  v += __shfl_down(v, 4);  v += __shfl_down(v, 2);  v += __shfl_down(v, 1);
  return v;
}
__device__ __forceinline__ float h2f_lo(unsigned u) {
  return __half2float(__ushort_as_half((unsigned short)(u & 0xffffu)));
}
__device__ __forceinline__ float h2f_hi(unsigned u) {
  return __half2float(__ushort_as_half((unsigned short)(u >> 16)));
}
__device__ __forceinline__ unsigned pack2h(float a, float b) {
  return (unsigned)__half_as_ushort(__float2half_rn(a)) |
         ((unsigned)__half_as_ushort(__float2half_rn(b)) << 16);
}

// ---- LLC-coherent (L1+L2 bypass) accessors ----
__device__ __forceinline__ float ld_cg_f32(const float* p) {
  float r;
  asm volatile("global_load_dword %0, %1, off sc0 sc1\n\ts_waitcnt vmcnt(0)"
               : "=v"(r) : "v"(p) : "memory");
  return r;
}
__device__ __forceinline__ void st_cg_f32(float* p, float v) {
  asm volatile("global_store_dword %0, %1, off sc0 sc1" :: "v"(p), "v"(v) : "memory");
}
__device__ __forceinline__ f4 ld_cg_f4(const f4* p) {
  f4 r;
  asm volatile("global_load_dwordx4 %0, %1, off sc0 sc1\n\ts_waitcnt vmcnt(0)"
               : "=v"(r) : "v"(p) : "memory");
  return r;
}
__device__ __forceinline__ void st_cg_f4(f4* p, f4 v) {
  asm volatile("global_store_dwordx4 %0, %1, off sc0 sc1" :: "v"(p), "v"(v) : "memory");
}
__device__ __forceinline__ void ld6_cg(f4& r0, f4& r1, f4& r2, f4& r3, f4& r4, f4& r5,
                                       const f4* a0, const f4* a1, const f4* a2,
                                       const f4* a3, const f4* a4, const f4* a5) {
  asm volatile(
    "global_load_dwordx4 %0, %6, off sc0 sc1\n\t"
    "global_load_dwordx4 %1, %7, off sc0 sc1\n\t"
    "global_load_dwordx4 %2, %8, off sc0 sc1\n\t"
    "global_load_dwordx4 %3, %9, off sc0 sc1\n\t"
    "global_load_dwordx4 %4, %10, off sc0 sc1\n\t"
    "global_load_dwordx4 %5, %11, off sc0 sc1\n\t"
    "s_waitcnt vmcnt(0)"
    : "=&v"(r0), "=&v"(r1), "=&v"(r2), "=&v"(r3), "=&v"(r4), "=&v"(r5)
    : "v"(a0), "v"(a1), "v"(a2), "v"(a3), "v"(a4), "v"(a5)
    : "memory");
}
__device__ __forceinline__ void ld8_cg(f4& r0, f4& r1, f4& r2, f4& r3,
                                       f4& r4, f4& r5, f4& r6, f4& r7,
                                       const f4* a0, const f4* a1, const f4* a2,
                                       const f4* a3, const f4* a4, const f4* a5,
                                       const f4* a6, const f4* a7) {
  asm volatile(
    "global_load_dwordx4 %0, %8, off sc0 sc1\n\t"
    "global_load_dwordx4 %1, %9, off sc0 sc1\n\t"
    "global_load_dwordx4 %2, %10, off sc0 sc1\n\t"
    "global_load_dwordx4 %3, %11, off sc0 sc1\n\t"
    "global_load_dwordx4 %4, %12, off sc0 sc1\n\t"
    "global_load_dwordx4 %5, %13, off sc0 sc1\n\t"
    "global_load_dwordx4 %6, %14, off sc0 sc1\n\t"
    "global_load_dwordx4 %7, %15, off sc0 sc1\n\t"
    "s_waitcnt vmcnt(0)"
    : "=&v"(r0), "=&v"(r1), "=&v"(r2), "=&v"(r3),
      "=&v"(r4), "=&v"(r5), "=&v"(r6), "=&v"(r7)
    : "v"(a0), "v"(a1), "v"(a2), "v"(a3),
      "v"(a4), "v"(a5), "v"(a6), "v"(a7)
    : "memory");
}

// ---------------- init: zero awc + ALL tagged record regions (replay safety) ----
__global__ void k_init(float* __restrict__ ws) {
  const int gid = blockIdx.x * 256 + threadIdx.x;
  float* awc = ws + OFF_AWC;
  for (int i = gid; i < NB*TE; i += 32*256) st_cg_f32(awc + i, 0.0f);
  f4* recs = (f4*)(ws + OFF_ENR);
  const int nrec = (OFF_END - OFF_ENR) / 4;
  const f4 z = (f4){0.f, 0.f, 0.f, 0.f};
  for (int i = gid; i < nrec; i += 32*256) st_cg_f4(recs + i, z);
}

// ---------------- prenet ----------------
__global__ void k_prenet(const float* __restrict__ mels,
                         const float* __restrict__ w1,
                         const float* __restrict__ w2,
                         float* __restrict__ x2) {
  const int t = blockIdx.x >> 4;
  const int b = blockIdx.x & 15;
  const int j = threadIdx.x;
  __shared__ float s_in[NMEL];
  __shared__ float s_x1[PREN];
  if (j < NMEL) s_in[j] = (t == 0) ? 0.0f : mels[(b*TD + (t-1))*NMEL + j];
  __syncthreads();
  float a1 = 0.0f;
  #pragma unroll 8
  for (int k = 0; k < NMEL; ++k) a1 += s_in[k] * w1[j*NMEL + k];
  s_x1[j] = fmaxf(a1, 0.0f);
  __syncthreads();
  float a2 = 0.0f;
  #pragma unroll 8
  for (int k = 0; k < PREN; ++k) a2 += s_x1[k] * w2[j*PREN + k];
  x2[(t*NB + b)*PREN + j] = fmaxf(a2, 0.0f);
}

// ---------------- processed encoder ----------------
__global__ void k_procenc(const float* __restrict__ enc,
                          const float* __restrict__ w,
                          float* __restrict__ pe) {
  const int bt = blockIdx.x;
  const int a = threadIdx.x;
  __shared__ float s_e[EE];
  for (int k = a; k < EE; k += 128) s_e[k] = enc[bt*EE + k];
  __syncthreads();
  float acc = 0.0f;
  #pragma unroll 8
  for (int k = 0; k < EE; ++k) acc += s_e[k] * w[a*EE + k];
  pe[bt*ATT + a] = acc;
}

// ---------------- main: pure-dataflow decoder, zero barriers ----------------
__global__ void __launch_bounds__(512, 1) k_main(
    const float* __restrict__ enc,
    const float* __restrict__ lstm_proj_w,
    const float* __restrict__ loc_conv_w,
    const float* __restrict__ loc_conv_b,
    const float* __restrict__ loc_dense_w,
    const float* __restrict__ loc_dense_b,
    const float* __restrict__ e_w,
    const float* __restrict__ e_b,
    const float* __restrict__ w_ih0,
    const float* __restrict__ b_ih0,
    const float* __restrict__ b_hh0,
    const float* __restrict__ w_ih1,
    const float* __restrict__ b_ih1,
    const float* __restrict__ b_hh1,
    const float* __restrict__ proj_w,
    const float* __restrict__ proj_b,
    const float* __restrict__ stop_w,
    const float* __restrict__ stop_b,
    const int*   __restrict__ text_len,
    float* __restrict__ ws,
    float* __restrict__ out) {
  const int bid = blockIdx.x;   // 0..255
  const int tid = threadIdx.x;  // 0..511

  float* x2  = ws + OFF_X2;
  float* pe  = ws + OFF_PE;
  float* awc = ws + OFF_AWC;
  f4* en_rec = (f4*)(ws + OFF_ENR);
  f4* qv_rec = (f4*)(ws + OFF_QVR);
  f4* ct_rec = (f4*)(ws + OFF_CTR);
  f4* h1_rec = (f4*)(ws + OFF_H1R);
  f4* h2_rec = (f4*)(ws + OFF_H2R);

  __shared__ __align__(16) float s_ldw[NLOC*ATT];   // loc_dense_w^T [c][a]
  __shared__ float s_awc[64];
  __shared__ float s_loc[16*33];
  __shared__ float s_red[16];
  __shared__ float s_en[256];
  __shared__ float s_aw[256];
  __shared__ float s_entmp[16];
  __shared__ float s_ctmp[32];
  __shared__ float s_qtmp[8];
  __shared__ __align__(16) float s_q[ATT];
  __shared__ __align__(16) float s_dec[HH+EE];      // [h2 f32 | ctx f32]
  __shared__ float s_b0[12], s_b1[12];
  extern __shared__ __align__(16) float dynlds[];
  f4* lw0x = (f4*)dynlds;                 // [12][64]
  f4* lw0c = lw0x + LW0X_F4;              // [12][177] (entry 176 = zero)
  f4* lw1  = lw0c + LW0C_F4;              // [12][256]

  const int b_grp = bid & 15;
  const int sub   = bid >> 4;
  const int h0    = bid * 4;

  // ---- one-time staging ----
  for (int i = tid; i < NLOC*ATT; i += 512) {
    int c = i >> 7, a = i & 127;
    s_ldw[i] = loc_dense_w[a*NLOC + c];
  }
  if (tid < 12) {
    int g = tid >> 2, h = tid & 3;
    int gr = (g == 0 ? 0 : (g == 1 ? 2048 : 3072)) + h0 + h;
    s_b0[tid] = b_ih0[gr] + b_hh0[gr];
    s_b1[tid] = b_ih1[gr] + b_hh1[gr];
  }
  {
    const f4* w0_4 = (const f4*)w_ih0;   // row stride 192 f4
    const f4* w1_4 = (const f4*)w_ih1;   // row stride 256 f4
    for (int i = tid; i < LW0X_F4; i += 512) {        // x-part: plain f4 cols
      int r = i >> 6, c = i & 63;
      int g = r >> 2, h = r & 3;
      int grow = (g == 0 ? 0 : (g == 1 ? 2048 : 3072)) + h0 + h;
      lw0x[i] = w0_4[grow*192 + c];
    }
    for (int i = tid; i < LW0C_F4; i += 512) {        // ctx-part: 3-packed + 0
      int r = i / 177, e = i - r*177;
      f4 v = (f4){0.f, 0.f, 0.f, 0.f};
      if (e < 176) {
        int g = r >> 2, h = r & 3;
        int grow = (g == 0 ? 0 : (g == 1 ? 2048 : 3072)) + h0 + h;
        int s = e / 11, rr = e - s*11;
        int base = s*32 + 3*rr;
        if (base + 0 < s*32 + 32) v.x = w_ih0[(size_t)grow*768 + 256 + base + 0];
        if (3*rr + 1 < 32)        v.y = w_ih0[(size_t)grow*768 + 256 + base + 1];
        if (3*rr + 2 < 32)        v.z = w_ih0[(size_t)grow*768 + 256 + base + 2];
      }
      lw0c[i] = v;
    }
    for (int i = tid; i < LW1_F4; i += 512) {
      int r = i >> 8, c = i & 255;
      int g = r >> 2, h = r & 3;
      int grow = (g == 0 ? 0 : (g == 1 ? 2048 : 3072)) + h0 + h;
      lw1[i] = w1_4[grow*256 + c];
    }
  }
  const int   lenb = text_len[b_grp];
  const float eb0  = e_b[0];

  // P1 per-thread invariants
  const int tl = tid >> 5;          // 0..15
  const int j  = tid & 31;          // 0..31
  float lcw_r[KWW];
  #pragma unroll
  for (int k = 0; k < KWW; ++k) lcw_r[k] = loc_conv_w[j*KWW + k];
  const float lcb_r = loc_conv_b[j];
  const f4 db_r = *(const f4*)(loc_dense_b + 4*j);
  const f4 ew_r = *(const f4*)(e_w + 4*j);
  const f4 pe_r = *(const f4*)(pe + (size_t)(b_grp*TE + sub*16 + tl)*ATT + 4*j);
  const f4 ps_r = pe_r + db_r;
  // P2 invariants: enc fragment in registers
  const int e4i = tid >> 6;         // 0..7
  const int ts  = tid & 63;         // 0..63
  f4 encr[4];
  {
    const f4* enc4 = (const f4*)(enc + (size_t)b_grp*TE*EE);
    #pragma unroll
    for (int i = 0; i < 4; ++i)
      encr[i] = enc4[(size_t)(ts + 64*i)*(EE/4) + sub*8 + e4i];
  }
  // P3/P4 mapping
  const int pb = tid >> 5;          // 0..15 batch
  const int kc = tid & 31;          // k-split 32
  // P3b record/weight indices (dummy slot -> rec 0, zero weight 176)
  int ridx[6], widx[6];
  #pragma unroll
  for (int i = 0; i < 6; ++i) {
    if (kc < 16) { ridx[i] = kc*6 + i; widx[i] = ridx[i]; }
    else if (i < 5) { ridx[i] = 96 + (kc-16)*5 + i; widx[i] = ridx[i]; }
    else { ridx[i] = 0; widx[i] = 176; }
  }
  __syncthreads();

  for (int t = 0; t < TD; ++t) {
    const unsigned tg = (unsigned)(t + 1);
    // ===== P1a: conv + loc_dense pre-term (needs only awc of prev step) =====
    f4 pre;
    {
      if (tid >= 128 && tid < 176) {
        const int i = tid - 128;
        const int g = sub*16 - PADW + i;
        s_awc[i] = (i < 46 && g >= 0 && g < TE) ? ld_cg_f32(awc + b_grp*TE + g)
                                                : 0.0f;
      }
      __syncthreads();
      float cv = lcb_r;
      #pragma unroll
      for (int k = 0; k < KWW; ++k) cv += s_awc[tl + k] * lcw_r[k];
      s_loc[tl*33 + j] = cv;
      __syncthreads();
      f4 d4 = (f4){0.f, 0.f, 0.f, 0.f};
      #pragma unroll 8
      for (int c = 0; c < NLOC; ++c) {
        const float lv = s_loc[tl*33 + c];
        const f4 w4 = ((const f4*)s_ldw)[c*32 + j];
        d4.x += lv*w4.x; d4.y += lv*w4.y; d4.z += lv*w4.z; d4.w += lv*w4.w;
      }
      pre = ps_r + d4;
    }
    // ===== P1b: poll qv (tag == t), energies, en records; mel[t-1] shadow =====
    {
      if (tid < 32) {
        const f4* qp = qv_rec + (b_grp*16 + (tid >> 1))*2 + (tid & 1);
        f4 r;
        do { r = ld_cg_f4(qp); } while (__float_as_uint(r.z) != (unsigned)t);
        const unsigned u0 = __float_as_uint(r.x), u1 = __float_as_uint(r.y);
        const int base = (tid >> 1)*8 + (tid & 1)*4;
        s_q[base+0] = h2f_lo(u0); s_q[base+1] = h2f_hi(u0);
        s_q[base+2] = h2f_lo(u1); s_q[base+3] = h2f_hi(u1);
      }
      __syncthreads();
      const f4 q4 = *(const f4*)(s_q + 4*j);
      float acc = tanhf(pre.x+q4.x)*ew_r.x + tanhf(pre.y+q4.y)*ew_r.y
                + tanhf(pre.z+q4.z)*ew_r.z + tanhf(pre.w+q4.w)*ew_r.w;
      acc = red32(acc);
      if (j == 0) {
        float evv = acc + eb0;
        const int tt = sub*16 + tl;
        if (tt >= lenb) evv = -1e9f;
        s_entmp[tl] = evv;
      }
      __syncthreads();
      if (tid < 6) {
        f4 r = (f4){0.f, 0.f, 0.f, __uint_as_float(tg)};
        const int base = 3*tid;
        r.x = s_entmp[base];
        if (base + 1 < 16) r.y = s_entmp[base+1];
        if (base + 2 < 16) r.z = s_entmp[base+2];
        st_cg_f4(en_rec + (b_grp*16 + sub)*6 + tid, r);
      }
      // mel/stop for t-1 (shadow; s_dec holds h2[t-1] | ctx[t-1])
      if (t > 0 && sub >= 8) {
        const int m = (sub - 8)*11 + tl;
        if (tl < 11 && m < 81) {
          const float* wrow = (m < NMEL) ? (proj_w + (size_t)m*(HH+EE)) : stop_w;
          const f4* w4 = (const f4*)wrow;
          const f4* s4 = (const f4*)s_dec;
          float a2 = 0.0f;
          #pragma unroll
          for (int i = 0; i < 12; ++i) a2 += dot4(s4[j + 32*i], w4[j + 32*i]);
          a2 = red32(a2);
          if (j == 0) {
            if (m < NMEL) out[(b_grp*TD + (t-1))*NMEL + m] = a2 + proj_b[m];
            else          out[NB*TD*NMEL + b_grp*TD + (t-1)] = a2 + stop_b[0];
          }
        }
      }
    }
    // ===== P2: poll en (tag t+1), softmax, awc, ctx records =====
    {
      if (tid < 96) {
        const int si = tid / 6, r = tid - si*6;
        const f4* ep = en_rec + (b_grp*16 + si)*6 + r;
        f4 v;
        do { v = ld_cg_f4(ep); } while (__float_as_uint(v.w) != tg);
        const int base = si*16 + 3*r;
        s_en[base] = v.x;
        if (3*r + 1 < 16) s_en[base+1] = v.y;
        if (3*r + 2 < 16) s_en[base+2] = v.z;
      }
      __syncthreads();
      float evv = 0.f, p = 0.f;
      if (tid < 256) {
        evv = s_en[tid];
        float m = evv;
        #pragma unroll
        for (int d = 32; d > 0; d >>= 1) m = fmaxf(m, __shfl_xor(m, d));
        if ((tid & 63) == 0) s_red[tid >> 6] = m;
      }
      __syncthreads();
      const float mx = fmaxf(fmaxf(s_red[0], s_red[1]), fmaxf(s_red[2], s_red[3]));
      if (tid < 256) {
        p = expf(evv - mx);
        float sm = p;
        #pragma unroll
        for (int d = 32; d > 0; d >>= 1) sm += __shfl_xor(sm, d);
        if ((tid & 63) == 0) s_red[8 + (tid >> 6)] = sm;
      }
      __syncthreads();
      const float inv = 1.0f / (s_red[8] + s_red[9] + s_red[10] + s_red[11]);
      if (tid < 256) {
        const float aw = p * inv;
        s_aw[tid] = aw;
        if (sub == 0) {
          const float old = ld_cg_f32(awc + b_grp*TE + tid);
          st_cg_f32(awc + b_grp*TE + tid, old + aw);
        }
      }
      __syncthreads();
      f4 a4 = (f4){0.f, 0.f, 0.f, 0.f};
      #pragma unroll
      for (int i = 0; i < 4; ++i) {
        const float awv = s_aw[ts + 64*i];
        a4.x += awv*encr[i].x; a4.y += awv*encr[i].y;
        a4.z += awv*encr[i].z; a4.w += awv*encr[i].w;
      }
      a4.x = red64(a4.x); a4.y = red64(a4.y); a4.z = red64(a4.z); a4.w = red64(a4.w);
      if (ts == 0) {
        s_ctmp[e4i*4+0] = a4.x; s_ctmp[e4i*4+1] = a4.y;
        s_ctmp[e4i*4+2] = a4.z; s_ctmp[e4i*4+3] = a4.w;
      }
      __syncthreads();   // drains awc stores (vmcnt) before ctx tags go out
      if (tid < 11) {
        f4 r = (f4){0.f, 0.f, 0.f, __uint_as_float(tg)};
        const int base = 3*tid;
        r.x = s_ctmp[base];
        if (base + 1 < 32) r.y = s_ctmp[base+1];
        if (base + 2 < 32) r.z = s_ctmp[base+2];
        st_cg_f4(ct_rec + b_grp*176 + sub*11 + tid, r);
      }
    }
    // ===== P3: LSTM0 (x-part plain, then poll ctx records) =====
    {
      float acc[12];
      #pragma unroll
      for (int r = 0; r < 12; ++r) acc[r] = 0.0f;
      const f4* x4p = (const f4*)(x2 + (size_t)(t*NB + pb)*PREN);
      #pragma unroll
      for (int i = 0; i < 2; ++i) {
        const int kf = kc + 32*i;
        const f4 xv = x4p[kf];
        #pragma unroll
        for (int r = 0; r < 12; ++r) acc[r] += dot4(xv, lw0x[r*64 + kf]);
      }
      const f4* cr = ct_rec + pb*176;
      f4 c0, c1, c2, c3, c4, c5;
      for (;;) {
        ld6_cg(c0, c1, c2, c3, c4, c5,
               cr+ridx[0], cr+ridx[1], cr+ridx[2], cr+ridx[3], cr+ridx[4], cr+ridx[5]);
        if (__float_as_uint(c0.w) == tg && __float_as_uint(c1.w) == tg &&
            __float_as_uint(c2.w) == tg && __float_as_uint(c3.w) == tg &&
            __float_as_uint(c4.w) == tg && __float_as_uint(c5.w) == tg) break;
      }
      // tag slot (.w) hits zero-padded weight slot -> free
      #pragma unroll
      for (int r = 0; r < 12; ++r) {
        acc[r] += dot4(c0, lw0c[r*177 + widx[0]]);
        acc[r] += dot4(c1, lw0c[r*177 + widx[1]]);
        acc[r] += dot4(c2, lw0c[r*177 + widx[2]]);
        acc[r] += dot4(c3, lw0c[r*177 + widx[3]]);
        acc[r] += dot4(c4, lw0c[r*177 + widx[4]]);
        acc[r] += dot4(c5, lw0c[r*177 + widx[5]]);
      }
      #pragma unroll
      for (int r = 0; r < 12; ++r) acc[r] = red32(acc[r]);
      if (kc == 0) {
        float hv[4];
        #pragma unroll
        for (int h = 0; h < 4; ++h) {
          const float gi = acc[h]   + s_b0[h];
          const float gg = acc[4+h] + s_b0[4+h];
          const float go = acc[8+h] + s_b0[8+h];
          hv[h] = sigmf(go) * tanhf(sigmf(gi) * tanhf(gg));
        }
        f4 r = (f4){__uint_as_float(pack2h(hv[0], hv[1])),
                    __uint_as_float(pack2h(hv[2], hv[3])),
                    __uint_as_float(tg), 0.f};
        st_cg_f4(h1_rec + pb*256 + bid, r);
      }
    }
    // ===== P4: LSTM1 (poll h1 records, fp16 payload) =====
    {
      float acc[12];
      #pragma unroll
      for (int r = 0; r < 12; ++r) acc[r] = 0.0f;
      const f4* hr = h1_rec + pb*256;
      f4 v0, v1, v2, v3, v4, v5, v6, v7;
      for (;;) {
        ld8_cg(v0, v1, v2, v3, v4, v5, v6, v7,
               hr+kc, hr+kc+32, hr+kc+64, hr+kc+96,
               hr+kc+128, hr+kc+160, hr+kc+192, hr+kc+224);
        if (__float_as_uint(v0.z) == tg && __float_as_uint(v1.z) == tg &&
            __float_as_uint(v2.z) == tg && __float_as_uint(v3.z) == tg &&
            __float_as_uint(v4.z) == tg && __float_as_uint(v5.z) == tg &&
            __float_as_uint(v6.z) == tg && __float_as_uint(v7.z) == tg) break;
      }
      f4 recs[8] = {v0, v1, v2, v3, v4, v5, v6, v7};
      #pragma unroll
      for (int i = 0; i < 8; ++i) {
        const unsigned u0 = __float_as_uint(recs[i].x);
        const unsigned u1 = __float_as_uint(recs[i].y);
        const float f0 = h2f_lo(u0), f1 = h2f_hi(u0);
        const float f2 = h2f_lo(u1), f3 = h2f_hi(u1);
        const int blk = kc + 32*i;
        #pragma unroll
        for (int r = 0; r < 12; ++r) {
          const f4 w = lw1[r*256 + blk];
          acc[r] += f0*w.x + f1*w.y + f2*w.z + f3*w.w;
        }
      }
      #pragma unroll
      for (int r = 0; r < 12; ++r) acc[r] = red32(acc[r]);
      if (kc == 0) {
        float hv[4];
        #pragma unroll
        for (int h = 0; h < 4; ++h) {
          const float gi = acc[h]   + s_b1[h];
          const float gg = acc[4+h] + s_b1[4+h];
          const float go = acc[8+h] + s_b1[8+h];
          hv[h] = sigmf(go) * tanhf(sigmf(gi) * tanhf(gg));
        }
        f4 r = (f4){__uint_as_float(pack2h(hv[0], hv[1])),
                    __uint_as_float(pack2h(hv[2], hv[3])),
                    __uint_as_float(tg), 0.f};
        st_cg_f4(h2_rec + pb*256 + bid, r);
      }
    }
    // ===== P5: poll h2 + ctx -> s_dec; qv records (8 rows per sub, fp16) =====
    {
      if (tid < 256) {
        const f4* hp = h2_rec + b_grp*256 + tid;
        f4 r;
        do { r = ld_cg_f4(hp); } while (__float_as_uint(r.z) != tg);
        const unsigned u0 = __float_as_uint(r.x), u1 = __float_as_uint(r.y);
        s_dec[4*tid+0] = h2f_lo(u0); s_dec[4*tid+1] = h2f_hi(u0);
        s_dec[4*tid+2] = h2f_lo(u1); s_dec[4*tid+3] = h2f_hi(u1);
      } else if (tid < 432) {
        const int i = tid - 256;
        const f4* cp = ct_rec + b_grp*176 + i;
        f4 r;
        do { r = ld_cg_f4(cp); } while (__float_as_uint(r.w) != tg);
        const int si = i / 11, rr = i - si*11;
        const int base = HH + si*32 + 3*rr;
        s_dec[base] = r.x;
        if (3*rr + 1 < 32) s_dec[base+1] = r.y;
        if (3*rr + 2 < 32) s_dec[base+2] = r.z;
      }
      __syncthreads();
      const int row = tid >> 6;        // 0..7 : one q-row per wave
      const int kq  = tid & 63;
      const int a   = sub*8 + row;
      const f4* s4 = (const f4*)s_dec;
      const f4* w4 = (const f4*)(lstm_proj_w + (size_t)a*HH);
      float a2 = 0.0f;
      #pragma unroll
      for (int i = 0; i < 4; ++i) a2 += dot4(s4[kq + 64*i], w4[kq + 64*i]);
      a2 = red64(a2);
      if (kq == 0) s_qtmp[row] = a2;
      __syncthreads();
      if (tid < 2) {
        f4 r = (f4){__uint_as_float(pack2h(s_qtmp[4*tid],   s_qtmp[4*tid+1])),
                    __uint_as_float(pack2h(s_qtmp[4*tid+2], s_qtmp[4*tid+3])),
                    __uint_as_float(tg), 0.f};
        st_cg_f4(qv_rec + (b_grp*16 + sub)*2 + tid, r);
      }
    }
  }
  // ===== epilogue: mel/stop for t = TD-1 (s_dec holds h2|ctx of last step) =====
  __syncthreads();
  if (sub >= 8) {
    const int m = (sub - 8)*11 + tl;
    if (tl < 11 && m < 81) {
      const float* wrow = (m < NMEL) ? (proj_w + (size_t)m*(HH+EE)) : stop_w;
      const f4* w4 = (const f4*)wrow;
      const f4* s4 = (const f4*)s_dec;
      float a2 = 0.0f;
      #pragma unroll
      for (int i = 0; i < 12; ++i) a2 += dot4(s4[j + 32*i], w4[j + 32*i]);
      a2 = red32(a2);
      if (j == 0) {
        if (m < NMEL) out[(b_grp*TD + (TD-1))*NMEL + m] = a2 + proj_b[m];
        else          out[NB*TD*NMEL + b_grp*TD + (TD-1)] = a2 + stop_b[0];
      }
    }
  }
}

extern "C" void kernel_launch(void* const* d_in, const int* in_sizes, int n_in,
                              void* d_out, int out_size, void* d_ws, size_t ws_size,
                              hipStream_t stream) {
  (void)in_sizes; (void)n_in; (void)out_size; (void)ws_size;
  const float* enc         = (const float*)d_in[0];
  const float* mels        = (const float*)d_in[1];
  const float* enc_proj_w  = (const float*)d_in[2];
  const float* lstm_proj_w = (const float*)d_in[3];
  const float* loc_conv_w  = (const float*)d_in[4];
  const float* loc_conv_b  = (const float*)d_in[5];
  const float* loc_dense_w = (const float*)d_in[6];
  const float* loc_dense_b = (const float*)d_in[7];
  const float* e_w         = (const float*)d_in[8];
  const float* e_b         = (const float*)d_in[9];
  const float* prenet1_w   = (const float*)d_in[10];
  const float* prenet2_w   = (const float*)d_in[11];
  const float* w_ih0       = (const float*)d_in[12];
  const float* b_ih0       = (const float*)d_in[14];
  const float* b_hh0       = (const float*)d_in[15];
  const float* w_ih1       = (const float*)d_in[16];
  const float* b_ih1       = (const float*)d_in[18];
  const float* b_hh1       = (const float*)d_in[19];
  const float* proj_w      = (const float*)d_in[20];
  const float* proj_b      = (const float*)d_in[21];
  const float* stop_w      = (const float*)d_in[22];
  const float* stop_b      = (const float*)d_in[23];
  const int*   text_len    = (const int*)d_in[24];
  float* ws  = (float*)d_ws;
  float* out = (float*)d_out;

  static int attr_set = 0;
  if (!attr_set) {
    hipFuncSetAttribute((const void*)k_main,
                        hipFuncAttributeMaxDynamicSharedMemorySize, DYN_BYTES);
    attr_set = 1;
  }

  k_init<<<dim3(32), dim3(256), 0, stream>>>(ws);
  k_prenet<<<dim3(TD*NB), dim3(256), 0, stream>>>(mels, prenet1_w, prenet2_w, ws + OFF_X2);
  k_procenc<<<dim3(NB*TE), dim3(128), 0, stream>>>(enc, enc_proj_w, ws + OFF_PE);

  k_main<<<dim3(256), dim3(512), DYN_BYTES, stream>>>(
      enc, lstm_proj_w, loc_conv_w, loc_conv_b, loc_dense_w, loc_dense_b,
      e_w, e_b, w_ih0, b_ih0, b_hh0, w_ih1, b_ih1, b_hh1,
      proj_w, proj_b, stop_w, stop_b, text_len, ws, out);
}

// Round 9
// 4330.753 us; speedup vs baseline: 1.5913x; 1.5913x over previous
//
#include <hip/hip_runtime.h>
#include <math.h>

#define NB   16
#define TE   256
#define TD   200
#define EE   512
#define ATT  128
#define PREN 256
#define HH   1024
#define NMEL 80
#define NLOC 32
#define KWW  31
#define PADW 15

// workspace offsets (float slots)
#define OFF_X2H  0                          // [TD][NB][128] u32 (256 fp16)
#define OFF_PE   (OFF_X2H + TD*NB*128)      // [NB][TE][ATT] f32
#define OFF_EN   (OFF_PE + NB*TE*ATT)       // [NB][TE] f32
#define OFF_CTH  (OFF_EN + NB*TE)           // [NB][256] u32 (512 fp16 ctx)
#define OFF_H1H  (OFF_CTH + NB*256)         // [NB][512] u32 (1024 fp16 h1)
#define OFF_H2R  (OFF_H1H + NB*512)         // [NB][256] f4 recs {h01,h23,tag,0}
#define OFF_QVR  (OFF_H2R + NB*256*4)       // [NB][16][2] f4 recs
#define OFF_BAR  (OFF_QVR + NB*16*2*4)      // flags
#define BAR_U32  8192
#define ARR_G 0
#define ARR_L 4096

// dynamic LDS (u32 counts): fp16-packed weight slices
#define LW0X_U32 (12*128)
#define LW0C_U32 (12*256)
#define LW1_U32  (12*512)
#define DYN_BYTES ((LW0X_U32 + LW0C_U32 + LW1_U32)*4)

typedef float f4 __attribute__((ext_vector_type(4)));
typedef unsigned int u32x4 __attribute__((ext_vector_type(4)));
typedef unsigned int u32x2 __attribute__((ext_vector_type(2)));
typedef _Float16 h2t __attribute__((ext_vector_type(2)));

__device__ __forceinline__ float sigmf(float x) { return 1.0f / (1.0f + expf(-x)); }
__device__ __forceinline__ float dot4(f4 a, f4 b) {
  return a.x*b.x + a.y*b.y + a.z*b.z + a.w*b.w;
}
__device__ __forceinline__ float red32(float v) {
  v += __shfl_down(v, 16, 32); v += __shfl_down(v, 8, 32);
  v += __shfl_down(v, 4, 32);  v += __shfl_down(v, 2, 32);
  v += __shfl_down(v, 1, 32);
  return v;
}
__device__ __forceinline__ float red64(float v) {
  v += __shfl_down(v, 32); v += __shfl_down(v, 16); v += __shfl_down(v, 8);
  v += __shfl_down(v, 4);  v += __shfl_down(v, 2);  v += __shfl_down(v, 1);
  return v;
}
__device__ __forceinline__ float fdot2(unsigned a, unsigned b, float c) {
  return __builtin_amdgcn_fdot2(__builtin_bit_cast(h2t, a),
                                __builtin_bit_cast(h2t, b), c, false);
}
__device__ __forceinline__ unsigned pkh(float a, float b) {
  h2t h; h.x = (_Float16)a; h.y = (_Float16)b;
  return __builtin_bit_cast(unsigned, h);
}
__device__ __forceinline__ float hlo(unsigned u) {
  return (float)__builtin_bit_cast(h2t, u).x;
}
__device__ __forceinline__ float hhi(unsigned u) {
  return (float)__builtin_bit_cast(h2t, u).y;
}

// ---- LLC-coherent (L1+L2 bypass) accessors ----
__device__ __forceinline__ unsigned ld_cg_u32(const unsigned* p) {
  unsigned r;
  asm volatile("global_load_dword %0, %1, off sc0 sc1\n\ts_waitcnt vmcnt(0)"
               : "=v"(r) : "v"(p) : "memory");
  return r;
}
__device__ __forceinline__ void st_cg_u32(unsigned* p, unsigned v) {
  asm volatile("global_store_dword %0, %1, off sc0 sc1" :: "v"(p), "v"(v) : "memory");
}
__device__ __forceinline__ float ld_cg_f32(const float* p) {
  float r;
  asm volatile("global_load_dword %0, %1, off sc0 sc1\n\ts_waitcnt vmcnt(0)"
               : "=v"(r) : "v"(p) : "memory");
  return r;
}
__device__ __forceinline__ void st_cg_f32(float* p, float v) {
  asm volatile("global_store_dword %0, %1, off sc0 sc1" :: "v"(p), "v"(v) : "memory");
}
__device__ __forceinline__ f4 ld_cg_f4(const f4* p) {
  f4 r;
  asm volatile("global_load_dwordx4 %0, %1, off sc0 sc1\n\ts_waitcnt vmcnt(0)"
               : "=v"(r) : "v"(p) : "memory");
  return r;
}
__device__ __forceinline__ void st_cg_f4(f4* p, f4 v) {
  asm volatile("global_store_dwordx4 %0, %1, off sc0 sc1" :: "v"(p), "v"(v) : "memory");
}
__device__ __forceinline__ u32x4 ld_cg_u4(const void* p) {
  u32x4 r;
  asm volatile("global_load_dwordx4 %0, %1, off sc0 sc1\n\ts_waitcnt vmcnt(0)"
               : "=v"(r) : "v"(p) : "memory");
  return r;
}
__device__ __forceinline__ void st_cg_u2(void* p, u32x2 v) {
  asm volatile("global_store_dwordx2 %0, %1, off sc0 sc1" :: "v"(p), "v"(v) : "memory");
}
__device__ __forceinline__ void ld2u(u32x4& a, u32x4& b, const void* pa, const void* pb) {
  asm volatile(
    "global_load_dwordx4 %0, %2, off sc0 sc1\n\t"
    "global_load_dwordx4 %1, %3, off sc0 sc1\n\t"
    "s_waitcnt vmcnt(0)"
    : "=&v"(a), "=&v"(b) : "v"(pa), "v"(pb) : "memory");
}
__device__ __forceinline__ void ld4u(u32x4& a, u32x4& b, u32x4& c, u32x4& d,
                                     const void* pa, const void* pb,
                                     const void* pc, const void* pd) {
  asm volatile(
    "global_load_dwordx4 %0, %4, off sc0 sc1\n\t"
    "global_load_dwordx4 %1, %5, off sc0 sc1\n\t"
    "global_load_dwordx4 %2, %6, off sc0 sc1\n\t"
    "global_load_dwordx4 %3, %7, off sc0 sc1\n\t"
    "s_waitcnt vmcnt(0)"
    : "=&v"(a), "=&v"(b), "=&v"(c), "=&v"(d)
    : "v"(pa), "v"(pb), "v"(pc), "v"(pd) : "memory");
}

// ---- all-to-all barriers (round-6 proven) ----
__device__ __forceinline__ void g_arrive(unsigned* bar, unsigned e) {
  __syncthreads();
  if (threadIdx.x == 0) st_cg_u32(bar + ARR_G + blockIdx.x * 16, e);
}
__device__ __forceinline__ void g_wait(unsigned* bar, unsigned e) {
  if (threadIdx.x < 256) {
    while (ld_cg_u32(bar + ARR_G + threadIdx.x * 16) < e) {}
  }
  __syncthreads();
}
__device__ __forceinline__ void l_arrive(unsigned* bar, unsigned e) {
  __syncthreads();
  if (threadIdx.x == 0) st_cg_u32(bar + ARR_L + blockIdx.x * 16, e);
}
__device__ __forceinline__ void l_wait(unsigned* bar, unsigned e, int b_grp) {
  if (threadIdx.x < 16) {
    while (ld_cg_u32(bar + ARR_L + (threadIdx.x * 16 + b_grp) * 16) < e) {}
  }
  __syncthreads();
}

// ---------------- init: zero flags + tagged record regions ----------------
__global__ void k_init(float* __restrict__ ws) {
  const int gid = blockIdx.x * 256 + threadIdx.x;
  f4* h2r = (f4*)(ws + OFF_H2R);
  f4* qvr = (f4*)(ws + OFF_QVR);
  unsigned* bar = (unsigned*)(ws + OFF_BAR);
  const f4 z = (f4){0.f, 0.f, 0.f, 0.f};
  for (int i = gid; i < NB*256; i += 32*256) st_cg_f4(h2r + i, z);
  for (int i = gid; i < NB*16*2; i += 32*256) st_cg_f4(qvr + i, z);
  for (int i = gid; i < BAR_U32; i += 32*256) st_cg_u32(bar + i, 0u);
}

// ---------------- prenet (fp16 output) ----------------
__global__ void k_prenet(const float* __restrict__ mels,
                         const float* __restrict__ w1,
                         const float* __restrict__ w2,
                         float* __restrict__ ws) {
  const int t = blockIdx.x >> 4;
  const int b = blockIdx.x & 15;
  const int j = threadIdx.x;
  __shared__ float s_in[NMEL];
  __shared__ float s_x1[PREN];
  if (j < NMEL) s_in[j] = (t == 0) ? 0.0f : mels[(b*TD + (t-1))*NMEL + j];
  __syncthreads();
  float a1 = 0.0f;
  #pragma unroll 8
  for (int k = 0; k < NMEL; ++k) a1 += s_in[k] * w1[j*NMEL + k];
  s_x1[j] = fmaxf(a1, 0.0f);
  __syncthreads();
  float a2 = 0.0f;
  #pragma unroll 8
  for (int k = 0; k < PREN; ++k) a2 += s_x1[k] * w2[j*PREN + k];
  ((_Float16*)(ws + OFF_X2H))[((size_t)t*NB + b)*256 + j] = (_Float16)fmaxf(a2, 0.0f);
}

// ---------------- processed encoder ----------------
__global__ void k_procenc(const float* __restrict__ enc,
                          const float* __restrict__ w,
                          float* __restrict__ pe) {
  const int bt = blockIdx.x;
  const int a = threadIdx.x;
  __shared__ float s_e[EE];
  for (int k = a; k < EE; k += 128) s_e[k] = enc[bt*EE + k];
  __syncthreads();
  float acc = 0.0f;
  #pragma unroll 8
  for (int k = 0; k < EE; ++k) acc += s_e[k] * w[a*EE + k];
  pe[bt*ATT + a] = acc;
}

// ---------------- main decoder loop ----------------
__global__ void __launch_bounds__(512, 1) k_main(
    const float* __restrict__ enc,
    const float* __restrict__ lstm_proj_w,
    const float* __restrict__ loc_conv_w,
    const float* __restrict__ loc_conv_b,
    const float* __restrict__ loc_dense_w,
    const float* __restrict__ loc_dense_b,
    const float* __restrict__ e_w,
    const float* __restrict__ e_b,
    const float* __restrict__ w_ih0,
    const float* __restrict__ b_ih0,
    const float* __restrict__ b_hh0,
    const float* __restrict__ w_ih1,
    const float* __restrict__ b_ih1,
    const float* __restrict__ b_hh1,
    const float* __restrict__ proj_w,
    const float* __restrict__ proj_b,
    const float* __restrict__ stop_w,
    const float* __restrict__ stop_b,
    const int*   __restrict__ text_len,
    float* __restrict__ ws,
    float* __restrict__ out) {
  const int bid = blockIdx.x;
  const int tid = threadIdx.x;

  const unsigned* x2h = (const unsigned*)(ws + OFF_X2H);
  float* pe  = ws + OFF_PE;
  float* en  = ws + OFF_EN;
  unsigned* cth = (unsigned*)(ws + OFF_CTH);
  unsigned* h1h = (unsigned*)(ws + OFF_H1H);
  f4* h2_rec = (f4*)(ws + OFF_H2R);
  f4* qv_rec = (f4*)(ws + OFF_QVR);
  unsigned* bar = (unsigned*)(ws + OFF_BAR);

  __shared__ __align__(16) float s_ldw[NLOC*ATT];   // loc_dense_w^T [c][a] f32
  __shared__ float s_awcf[TE];                      // local cumulative attn
  __shared__ float s_loc[16*33];
  __shared__ float s_red[16];
  __shared__ float s_aw[256];
  __shared__ float s_qtmp[8];
  __shared__ float s_ctmp[32];
  __shared__ __align__(16) float s_q[ATT];
  __shared__ __align__(16) float s_dec[HH+EE];      // [h2 f32 | ctx f32]
  __shared__ float s_b0[12], s_b1[12];
  extern __shared__ __align__(16) unsigned dynlds_u[];
  unsigned* lw0x = dynlds_u;                 // [12][128] u32
  unsigned* lw0c = lw0x + LW0X_U32;          // [12][256] u32
  unsigned* lw1  = lw0c + LW0C_U32;          // [12][512] u32

  const int b_grp = bid & 15;
  const int sub   = bid >> 4;
  const int h0    = bid * 4;

  // ---- one-time staging ----
  for (int i = tid; i < NLOC*ATT; i += 512) {
    int c = i >> 7, a = i & 127;
    s_ldw[i] = loc_dense_w[a*NLOC + c];
  }
  if (tid < 12) {
    int g = tid >> 2, h = tid & 3;
    int gr = (g == 0 ? 0 : (g == 1 ? 2048 : 3072)) + h0 + h;
    s_b0[tid] = b_ih0[gr] + b_hh0[gr];
    s_b1[tid] = b_ih1[gr] + b_hh1[gr];
  }
  for (int i = tid; i < LW0X_U32; i += 512) {
    int r = i >> 7, c = i & 127;
    int g = r >> 2, h = r & 3;
    int grow = (g == 0 ? 0 : (g == 1 ? 2048 : 3072)) + h0 + h;
    const float* wr = w_ih0 + (size_t)grow*768;
    lw0x[i] = pkh(wr[2*c], wr[2*c+1]);
  }
  for (int i = tid; i < LW0C_U32; i += 512) {
    int r = i >> 8, c = i & 255;
    int g = r >> 2, h = r & 3;
    int grow = (g == 0 ? 0 : (g == 1 ? 2048 : 3072)) + h0 + h;
    const float* wr = w_ih0 + (size_t)grow*768 + 256;
    lw0c[i] = pkh(wr[2*c], wr[2*c+1]);
  }
  for (int i = tid; i < LW1_U32; i += 512) {
    int r = i >> 9, c = i & 511;
    int g = r >> 2, h = r & 3;
    int grow = (g == 0 ? 0 : (g == 1 ? 2048 : 3072)) + h0 + h;
    const float* wr = w_ih1 + (size_t)grow*1024;
    lw1[i] = pkh(wr[2*c], wr[2*c+1]);
  }
  if (tid < 256) s_awcf[tid] = 0.0f;

  const int   lenb = text_len[b_grp];
  const float eb0  = e_b[0];
  // P1 invariants
  const int tl = tid >> 5;
  const int j  = tid & 31;
  float lcw_r[KWW];
  #pragma unroll
  for (int k = 0; k < KWW; ++k) lcw_r[k] = loc_conv_w[j*KWW + k];
  const float lcb_r = loc_conv_b[j];
  const f4 db_r = *(const f4*)(loc_dense_b + 4*j);
  const f4 ew_r = *(const f4*)(e_w + 4*j);
  const f4 pe_r = *(const f4*)(pe + (size_t)(b_grp*TE + sub*16 + tl)*ATT + 4*j);
  const f4 ps_r = pe_r + db_r;
  // P2 invariants: enc fragment in registers
  const int e4i = tid >> 6;
  const int ts  = tid & 63;
  f4 encr[4];
  {
    const f4* enc4 = (const f4*)(enc + (size_t)b_grp*TE*EE);
    #pragma unroll
    for (int i = 0; i < 4; ++i)
      encr[i] = enc4[(size_t)(ts + 64*i)*(EE/4) + sub*8 + e4i];
  }
  // P3/P4 mapping
  const int pb = tid >> 5;
  const int kc = tid & 31;
  __syncthreads();

  unsigned eg = 0, el = 0;

  for (int t = 0; t < TD; ++t) {
    const unsigned tg = (unsigned)(t + 1);
    // ===== P1a: conv from s_awcf + loc_dense pre-term (all-LDS) =====
    f4 pre;
    {
      float cv = lcb_r;
      const int pos = sub*16 + tl;
      #pragma unroll
      for (int k = 0; k < KWW; ++k) {
        const int g = pos - PADW + k;
        const float av = (g >= 0 && g < TE) ? s_awcf[g] : 0.0f;
        cv += av * lcw_r[k];
      }
      s_loc[tl*33 + j] = cv;
      __syncthreads();
      f4 d4 = (f4){0.f, 0.f, 0.f, 0.f};
      #pragma unroll 8
      for (int c = 0; c < NLOC; ++c) {
        const float lv = s_loc[tl*33 + c];
        const f4 w4 = ((const f4*)s_ldw)[c*32 + j];
        d4.x += lv*w4.x; d4.y += lv*w4.y; d4.z += lv*w4.z; d4.w += lv*w4.w;
      }
      pre = ps_r + d4;
    }
    // ===== P1b: poll qv recs (tag==t), energies, en store =====
    {
      if (tid < 32) {
        const int src = tid >> 1, r = tid & 1;
        const f4* qp = qv_rec + (b_grp*16 + src)*2 + r;
        f4 v;
        do { v = ld_cg_f4(qp); } while (__float_as_uint(v.z) != (unsigned)t);
        const unsigned u0 = __float_as_uint(v.x), u1 = __float_as_uint(v.y);
        const int base = src*8 + r*4;
        s_q[base+0] = hlo(u0); s_q[base+1] = hhi(u0);
        s_q[base+2] = hlo(u1); s_q[base+3] = hhi(u1);
      }
      __syncthreads();
      const f4 q4 = *(const f4*)(s_q + 4*j);
      float acc = tanhf(pre.x+q4.x)*ew_r.x + tanhf(pre.y+q4.y)*ew_r.y
                + tanhf(pre.z+q4.z)*ew_r.z + tanhf(pre.w+q4.w)*ew_r.w;
      acc = red32(acc);
      if (j == 0) {
        float evv = acc + eb0;
        const int tt = sub*16 + tl;
        if (tt >= lenb) evv = -1e9f;
        st_cg_f32(en + b_grp*TE + tt, evv);
      }
    }
    l_arrive(bar, ++el);
    // ===== mel/stop shadow for t-1 (s_dec intact from prev P5) =====
    if (t > 0) {
      const int ol = tid >> 5, kq = tid & 31;
      if (ol < 6) {
        const int m = sub*6 + ol;
        if (m < 81) {
          const float* wrow = (m < NMEL) ? (proj_w + (size_t)m*(HH+EE)) : stop_w;
          const f4* w4 = (const f4*)wrow;
          const f4* s4 = (const f4*)s_dec;
          float a2 = 0.0f;
          #pragma unroll
          for (int i = 0; i < 12; ++i) a2 += dot4(s4[kq + 32*i], w4[kq + 32*i]);
          a2 = red32(a2);
          if (kq == 0) {
            if (m < NMEL) out[(b_grp*TD + (t-1))*NMEL + m] = a2 + proj_b[m];
            else          out[NB*TD*NMEL + b_grp*TD + (t-1)] = a2 + stop_b[0];
          }
        }
      }
    }
    l_wait(bar, el, b_grp);
    // ===== P2: softmax + local awc + ctx (fp16 store) =====
    {
      float evv = 0.f, p = 0.f;
      if (tid < 256) {
        evv = ld_cg_f32(en + b_grp*TE + tid);
        float m = evv;
        #pragma unroll
        for (int d = 32; d > 0; d >>= 1) m = fmaxf(m, __shfl_xor(m, d));
        if ((tid & 63) == 0) s_red[tid >> 6] = m;
      }
      __syncthreads();
      const float mx = fmaxf(fmaxf(s_red[0], s_red[1]), fmaxf(s_red[2], s_red[3]));
      if (tid < 256) {
        p = expf(evv - mx);
        float sm = p;
        #pragma unroll
        for (int d = 32; d > 0; d >>= 1) sm += __shfl_xor(sm, d);
        if ((tid & 63) == 0) s_red[8 + (tid >> 6)] = sm;
      }
      __syncthreads();
      const float inv = 1.0f / (s_red[8] + s_red[9] + s_red[10] + s_red[11]);
      if (tid < 256) {
        const float aw = p * inv;
        s_aw[tid] = aw;
        s_awcf[tid] += aw;
      }
      __syncthreads();
      f4 a4 = (f4){0.f, 0.f, 0.f, 0.f};
      #pragma unroll
      for (int i = 0; i < 4; ++i) {
        const float awv = s_aw[ts + 64*i];
        a4.x += awv*encr[i].x; a4.y += awv*encr[i].y;
        a4.z += awv*encr[i].z; a4.w += awv*encr[i].w;
      }
      a4.x = red64(a4.x); a4.y = red64(a4.y); a4.z = red64(a4.z); a4.w = red64(a4.w);
      if (ts == 0) {
        s_ctmp[e4i*4+0] = a4.x; s_ctmp[e4i*4+1] = a4.y;
        s_ctmp[e4i*4+2] = a4.z; s_ctmp[e4i*4+3] = a4.w;
      }
      __syncthreads();
      if (tid < 4) {
        u32x4 w;
        w.x = pkh(s_ctmp[8*tid+0], s_ctmp[8*tid+1]);
        w.y = pkh(s_ctmp[8*tid+2], s_ctmp[8*tid+3]);
        w.z = pkh(s_ctmp[8*tid+4], s_ctmp[8*tid+5]);
        w.w = pkh(s_ctmp[8*tid+6], s_ctmp[8*tid+7]);
        u32x4* dst = (u32x4*)cth + b_grp*64 + sub*4 + tid;
        asm volatile("global_store_dwordx4 %0, %1, off sc0 sc1" :: "v"(dst), "v"(w) : "memory");
      }
    }
    g_arrive(bar, ++eg);
    // ===== P3a: LSTM0 x-part (fp16 dot2, independent of ctx) =====
    float acc[12];
    {
      #pragma unroll
      for (int r = 0; r < 12; ++r) acc[r] = 0.0f;
      // x2h row = 256 fp16 = 128 u32 = 32 u32x4  (round-8 bug: *64 OOB -> NaN)
      const u32x4 xv = ((const u32x4*)x2h)[((size_t)t*NB + pb)*32 + kc];
      #pragma unroll
      for (int r = 0; r < 12; ++r) {
        const u32x4 w = ((const u32x4*)lw0x)[r*32 + kc];
        acc[r] = fdot2(xv.x, w.x, acc[r]); acc[r] = fdot2(xv.y, w.y, acc[r]);
        acc[r] = fdot2(xv.z, w.z, acc[r]); acc[r] = fdot2(xv.w, w.w, acc[r]);
      }
    }
    g_wait(bar, eg);                  // ctx ready
    // ===== P3b: LSTM0 ctx-part + gates -> h1 fp16 =====
    {
      u32x4 c0, c1;
      const u32x4* cp = (const u32x4*)cth + pb*64 + kc*2;
      ld2u(c0, c1, cp, cp + 1);
      #pragma unroll
      for (int r = 0; r < 12; ++r) {
        const u32x4 w0 = ((const u32x4*)lw0c)[r*64 + kc*2];
        const u32x4 w1 = ((const u32x4*)lw0c)[r*64 + kc*2 + 1];
        acc[r] = fdot2(c0.x, w0.x, acc[r]); acc[r] = fdot2(c0.y, w0.y, acc[r]);
        acc[r] = fdot2(c0.z, w0.z, acc[r]); acc[r] = fdot2(c0.w, w0.w, acc[r]);
        acc[r] = fdot2(c1.x, w1.x, acc[r]); acc[r] = fdot2(c1.y, w1.y, acc[r]);
        acc[r] = fdot2(c1.z, w1.z, acc[r]); acc[r] = fdot2(c1.w, w1.w, acc[r]);
      }
      #pragma unroll
      for (int r = 0; r < 12; ++r) acc[r] = red32(acc[r]);
      if (kc == 0) {
        float hv[4];
        #pragma unroll
        for (int h = 0; h < 4; ++h) {
          const float gi = acc[h]   + s_b0[h];
          const float gg = acc[4+h] + s_b0[4+h];
          const float go = acc[8+h] + s_b0[8+h];
          hv[h] = sigmf(go) * tanhf(sigmf(gi) * tanhf(gg));
        }
        u32x2 stv; stv.x = pkh(hv[0], hv[1]); stv.y = pkh(hv[2], hv[3]);
        st_cg_u2((u32x2*)h1h + pb*256 + bid, stv);
      }
    }
    g_arrive(bar, ++eg);
    g_wait(bar, eg);                  // h1 ready
    // ===== P4: LSTM1 (fp16 dot2) -> h2 tagged rec =====
    {
      #pragma unroll
      for (int r = 0; r < 12; ++r) acc[r] = 0.0f;
      u32x4 v0, v1, v2, v3;
      const u32x4* hp = (const u32x4*)h1h + pb*128 + kc*4;
      ld4u(v0, v1, v2, v3, hp, hp+1, hp+2, hp+3);
      #pragma unroll
      for (int r = 0; r < 12; ++r) {
        const u32x4* wp = (const u32x4*)lw1 + r*128 + kc*4;
        const u32x4 w0 = wp[0], w1 = wp[1], w2 = wp[2], w3 = wp[3];
        acc[r] = fdot2(v0.x, w0.x, acc[r]); acc[r] = fdot2(v0.y, w0.y, acc[r]);
        acc[r] = fdot2(v0.z, w0.z, acc[r]); acc[r] = fdot2(v0.w, w0.w, acc[r]);
        acc[r] = fdot2(v1.x, w1.x, acc[r]); acc[r] = fdot2(v1.y, w1.y, acc[r]);
        acc[r] = fdot2(v1.z, w1.z, acc[r]); acc[r] = fdot2(v1.w, w1.w, acc[r]);
        acc[r] = fdot2(v2.x, w2.x, acc[r]); acc[r] = fdot2(v2.y, w2.y, acc[r]);
        acc[r] = fdot2(v2.z, w2.z, acc[r]); acc[r] = fdot2(v2.w, w2.w, acc[r]);
        acc[r] = fdot2(v3.x, w3.x, acc[r]); acc[r] = fdot2(v3.y, w3.y, acc[r]);
        acc[r] = fdot2(v3.z, w3.z, acc[r]); acc[r] = fdot2(v3.w, w3.w, acc[r]);
      }
      #pragma unroll
      for (int r = 0; r < 12; ++r) acc[r] = red32(acc[r]);
      if (kc == 0) {
        float hv[4];
        #pragma unroll
        for (int h = 0; h < 4; ++h) {
          const float gi = acc[h]   + s_b1[h];
          const float gg = acc[4+h] + s_b1[4+h];
          const float go = acc[8+h] + s_b1[8+h];
          hv[h] = sigmf(go) * tanhf(sigmf(gi) * tanhf(gg));
        }
        f4 r;
        r.x = __uint_as_float(pkh(hv[0], hv[1]));
        r.y = __uint_as_float(pkh(hv[2], hv[3]));
        r.z = __uint_as_float(tg); r.w = 0.f;
        st_cg_f4(h2_rec + pb*256 + bid, r);
      }
    }
    // ===== P5: poll h2 recs -> s_dec ; ctx -> s_dec ; q -> qv recs =====
    {
      if (tid < 256) {
        const f4* hp = h2_rec + b_grp*256 + tid;
        f4 v;
        do { v = ld_cg_f4(hp); } while (__float_as_uint(v.z) != tg);
        const unsigned u0 = __float_as_uint(v.x), u1 = __float_as_uint(v.y);
        s_dec[4*tid+0] = hlo(u0); s_dec[4*tid+1] = hhi(u0);
        s_dec[4*tid+2] = hlo(u1); s_dec[4*tid+3] = hhi(u1);
      } else if (tid < 320) {
        const int i = tid - 256;
        const u32x4 cv = ld_cg_u4((const u32x4*)cth + b_grp*64 + i);
        s_dec[HH + 8*i + 0] = hlo(cv.x); s_dec[HH + 8*i + 1] = hhi(cv.x);
        s_dec[HH + 8*i + 2] = hlo(cv.y); s_dec[HH + 8*i + 3] = hhi(cv.y);
        s_dec[HH + 8*i + 4] = hlo(cv.z); s_dec[HH + 8*i + 5] = hhi(cv.z);
        s_dec[HH + 8*i + 6] = hlo(cv.w); s_dec[HH + 8*i + 7] = hhi(cv.w);
      }
      __syncthreads();
      const int row = tid >> 6;
      const int kq  = tid & 63;
      const int a   = sub*8 + row;
      const f4* w4 = (const f4*)(lstm_proj_w + (size_t)a*HH);
      const f4* s4 = (const f4*)s_dec;
      float a2 = 0.0f;
      #pragma unroll
      for (int i = 0; i < 4; ++i) a2 += dot4(s4[kq + 64*i], w4[kq + 64*i]);
      a2 = red64(a2);
      if (kq == 0) s_qtmp[row] = a2;
      __syncthreads();
      if (tid < 2) {
        f4 r;
        r.x = __uint_as_float(pkh(s_qtmp[4*tid+0], s_qtmp[4*tid+1]));
        r.y = __uint_as_float(pkh(s_qtmp[4*tid+2], s_qtmp[4*tid+3]));
        r.z = __uint_as_float(tg); r.w = 0.f;
        st_cg_f4(qv_rec + (b_grp*16 + sub)*2 + tid, r);
      }
    }
  }
  // ===== epilogue: mel/stop for t = TD-1 =====
  __syncthreads();
  {
    const int ol = tid >> 5, kq = tid & 31;
    if (ol < 6) {
      const int m = sub*6 + ol;
      if (m < 81) {
        const float* wrow = (m < NMEL) ? (proj_w + (size_t)m*(HH+EE)) : stop_w;
        const f4* w4 = (const f4*)wrow;
        const f4* s4 = (const f4*)s_dec;
        float a2 = 0.0f;
        #pragma unroll
        for (int i = 0; i < 12; ++i) a2 += dot4(s4[kq + 32*i], w4[kq + 32*i]);
        a2 = red32(a2);
        if (kq == 0) {
          if (m < NMEL) out[(b_grp*TD + (TD-1))*NMEL + m] = a2 + proj_b[m];
          else          out[NB*TD*NMEL + b_grp*TD + (TD-1)] = a2 + stop_b[0];
        }
      }
    }
  }
}

extern "C" void kernel_launch(void* const* d_in, const int* in_sizes, int n_in,
                              void* d_out, int out_size, void* d_ws, size_t ws_size,
                              hipStream_t stream) {
  (void)in_sizes; (void)n_in; (void)out_size; (void)ws_size;
  const float* enc         = (const float*)d_in[0];
  const float* mels        = (const float*)d_in[1];
  const float* enc_proj_w  = (const float*)d_in[2];
  const float* lstm_proj_w = (const float*)d_in[3];
  const float* loc_conv_w  = (const float*)d_in[4];
  const float* loc_conv_b  = (const float*)d_in[5];
  const float* loc_dense_w = (const float*)d_in[6];
  const float* loc_dense_b = (const float*)d_in[7];
  const float* e_w         = (const float*)d_in[8];
  const float* e_b         = (const float*)d_in[9];
  const float* prenet1_w   = (const float*)d_in[10];
  const float* prenet2_w   = (const float*)d_in[11];
  const float* w_ih0       = (const float*)d_in[12];
  const float* b_ih0       = (const float*)d_in[14];
  const float* b_hh0       = (const float*)d_in[15];
  const float* w_ih1       = (const float*)d_in[16];
  const float* b_ih1       = (const float*)d_in[18];
  const float* b_hh1       = (const float*)d_in[19];
  const float* proj_w      = (const float*)d_in[20];
  const float* proj_b      = (const float*)d_in[21];
  const float* stop_w      = (const float*)d_in[22];
  const float* stop_b      = (const float*)d_in[23];
  const int*   text_len    = (const int*)d_in[24];
  float* ws  = (float*)d_ws;
  float* out = (float*)d_out;

  static int attr_set = 0;
  if (!attr_set) {
    hipFuncSetAttribute((const void*)k_main,
                        hipFuncAttributeMaxDynamicSharedMemorySize, DYN_BYTES);
    attr_set = 1;
  }

  k_init<<<dim3(32), dim3(256), 0, stream>>>(ws);
  k_prenet<<<dim3(TD*NB), dim3(256), 0, stream>>>(mels, prenet1_w, prenet2_w, ws);
  k_procenc<<<dim3(NB*TE), dim3(128), 0, stream>>>(enc, enc_proj_w, ws + OFF_PE);

  k_main<<<dim3(256), dim3(512), DYN_BYTES, stream>>>(
      enc, lstm_proj_w, loc_conv_w, loc_conv_b, loc_dense_w, loc_dense_b,
      e_w, e_b, w_ih0, b_ih0, b_hh0, w_ih1, b_ih1, b_hh1,
      proj_w, proj_b, stop_w, stop_b, text_len, ws, out);
}

// Round 10
// 3934.322 us; speedup vs baseline: 1.7516x; 1.1008x over previous
//
#include <hip/hip_runtime.h>
#include <math.h>

#define NB   16
#define TE   256
#define TD   200
#define EE   512
#define ATT  128
#define PREN 256
#define HH   1024
#define NMEL 80
#define NLOC 32
#define KWW  31
#define PADW 15

// workspace offsets (float slots)
#define OFF_X2H  0                          // [TD][NB][128] u32 (256 fp16)
#define OFF_PE   (OFF_X2H + TD*NB*128)      // [NB][TE][ATT] f32
#define OFF_EN   (OFF_PE + NB*TE*ATT)       // [NB][TE] f32
#define OFF_CTH  (OFF_EN + NB*TE)           // [NB][256] u32 (512 fp16 ctx)
#define OFF_H1H  (OFF_CTH + NB*256)         // [NB][512] u32 (1024 fp16 h1)
#define OFF_H2R  (OFF_H1H + NB*512)         // [NB][256] f4 recs {h01,h23,tag,0}
#define OFF_QVR  (OFF_H2R + NB*256*4)       // [NB][16][2] f4 recs
#define OFF_BAR  (OFF_QVR + NB*16*2*4)      // flags
#define BAR_U32  8192
#define ARR_G 0
#define ARR_L 4096

// dynamic LDS (u32 counts): fp16-packed weight slices
#define LW0X_U32 (12*128)
#define LW0C_U32 (12*256)
#define LW1_U32  (12*512)
#define DYN_BYTES ((LW0X_U32 + LW0C_U32 + LW1_U32)*4)

typedef float f4 __attribute__((ext_vector_type(4)));
typedef unsigned int u32x4 __attribute__((ext_vector_type(4)));
typedef unsigned int u32x2 __attribute__((ext_vector_type(2)));
typedef _Float16 h2t __attribute__((ext_vector_type(2)));

__device__ __forceinline__ float sigmf(float x) { return 1.0f / (1.0f + expf(-x)); }
__device__ __forceinline__ float dot4(f4 a, f4 b) {
  return a.x*b.x + a.y*b.y + a.z*b.z + a.w*b.w;
}
__device__ __forceinline__ float red32(float v) {
  v += __shfl_down(v, 16, 32); v += __shfl_down(v, 8, 32);
  v += __shfl_down(v, 4, 32);  v += __shfl_down(v, 2, 32);
  v += __shfl_down(v, 1, 32);
  return v;
}
__device__ __forceinline__ float red64(float v) {
  v += __shfl_down(v, 32); v += __shfl_down(v, 16); v += __shfl_down(v, 8);
  v += __shfl_down(v, 4);  v += __shfl_down(v, 2);  v += __shfl_down(v, 1);
  return v;
}
__device__ __forceinline__ float fdot2(unsigned a, unsigned b, float c) {
  return __builtin_amdgcn_fdot2(__builtin_bit_cast(h2t, a),
                                __builtin_bit_cast(h2t, b), c, false);
}
__device__ __forceinline__ unsigned pkh(float a, float b) {
  h2t h; h.x = (_Float16)a; h.y = (_Float16)b;
  return __builtin_bit_cast(unsigned, h);
}
__device__ __forceinline__ float hlo(unsigned u) {
  return (float)__builtin_bit_cast(h2t, u).x;
}
__device__ __forceinline__ float hhi(unsigned u) {
  return (float)__builtin_bit_cast(h2t, u).y;
}

// ---- LLC-coherent (L1+L2 bypass) accessors ----
__device__ __forceinline__ unsigned ld_cg_u32(const unsigned* p) {
  unsigned r;
  asm volatile("global_load_dword %0, %1, off sc0 sc1\n\ts_waitcnt vmcnt(0)"
               : "=v"(r) : "v"(p) : "memory");
  return r;
}
__device__ __forceinline__ void st_cg_u32(unsigned* p, unsigned v) {
  asm volatile("global_store_dword %0, %1, off sc0 sc1" :: "v"(p), "v"(v) : "memory");
}
__device__ __forceinline__ float ld_cg_f32(const float* p) {
  float r;
  asm volatile("global_load_dword %0, %1, off sc0 sc1\n\ts_waitcnt vmcnt(0)"
               : "=v"(r) : "v"(p) : "memory");
  return r;
}
__device__ __forceinline__ void st_cg_f32(float* p, float v) {
  asm volatile("global_store_dword %0, %1, off sc0 sc1" :: "v"(p), "v"(v) : "memory");
}
__device__ __forceinline__ f4 ld_cg_f4(const f4* p) {
  f4 r;
  asm volatile("global_load_dwordx4 %0, %1, off sc0 sc1\n\ts_waitcnt vmcnt(0)"
               : "=v"(r) : "v"(p) : "memory");
  return r;
}
__device__ __forceinline__ void st_cg_f4(f4* p, f4 v) {
  asm volatile("global_store_dwordx4 %0, %1, off sc0 sc1" :: "v"(p), "v"(v) : "memory");
}
__device__ __forceinline__ u32x4 ld_cg_u4(const void* p) {
  u32x4 r;
  asm volatile("global_load_dwordx4 %0, %1, off sc0 sc1\n\ts_waitcnt vmcnt(0)"
               : "=v"(r) : "v"(p) : "memory");
  return r;
}
__device__ __forceinline__ void st_cg_u2(void* p, u32x2 v) {
  asm volatile("global_store_dwordx2 %0, %1, off sc0 sc1" :: "v"(p), "v"(v) : "memory");
}
__device__ __forceinline__ void ld2u(u32x4& a, u32x4& b, const void* pa, const void* pb) {
  asm volatile(
    "global_load_dwordx4 %0, %2, off sc0 sc1\n\t"
    "global_load_dwordx4 %1, %3, off sc0 sc1\n\t"
    "s_waitcnt vmcnt(0)"
    : "=&v"(a), "=&v"(b) : "v"(pa), "v"(pb) : "memory");
}
__device__ __forceinline__ void ld4u(u32x4& a, u32x4& b, u32x4& c, u32x4& d,
                                     const void* pa, const void* pb,
                                     const void* pc, const void* pd) {
  asm volatile(
    "global_load_dwordx4 %0, %4, off sc0 sc1\n\t"
    "global_load_dwordx4 %1, %5, off sc0 sc1\n\t"
    "global_load_dwordx4 %2, %6, off sc0 sc1\n\t"
    "global_load_dwordx4 %3, %7, off sc0 sc1\n\t"
    "s_waitcnt vmcnt(0)"
    : "=&v"(a), "=&v"(b), "=&v"(c), "=&v"(d)
    : "v"(pa), "v"(pb), "v"(pc), "v"(pd) : "memory");
}

// ---- all-to-all barriers (round-6 proven) ----
__device__ __forceinline__ void g_arrive(unsigned* bar, unsigned e) {
  __syncthreads();
  if (threadIdx.x == 0) st_cg_u32(bar + ARR_G + blockIdx.x * 16, e);
}
__device__ __forceinline__ void g_wait(unsigned* bar, unsigned e) {
  if (threadIdx.x < 256) {
    while (ld_cg_u32(bar + ARR_G + threadIdx.x * 16) < e) {}
  }
  __syncthreads();
}
__device__ __forceinline__ void l_arrive(unsigned* bar, unsigned e) {
  __syncthreads();
  if (threadIdx.x == 0) st_cg_u32(bar + ARR_L + blockIdx.x * 16, e);
}
__device__ __forceinline__ void l_wait(unsigned* bar, unsigned e, int b_grp) {
  if (threadIdx.x < 16) {
    while (ld_cg_u32(bar + ARR_L + (threadIdx.x * 16 + b_grp) * 16) < e) {}
  }
  __syncthreads();
}

// ---------------- init: zero flags + tagged record regions ----------------
__global__ void k_init(float* __restrict__ ws) {
  const int gid = blockIdx.x * 256 + threadIdx.x;
  f4* h2r = (f4*)(ws + OFF_H2R);
  f4* qvr = (f4*)(ws + OFF_QVR);
  unsigned* bar = (unsigned*)(ws + OFF_BAR);
  const f4 z = (f4){0.f, 0.f, 0.f, 0.f};
  for (int i = gid; i < NB*256; i += 32*256) st_cg_f4(h2r + i, z);
  for (int i = gid; i < NB*16*2; i += 32*256) st_cg_f4(qvr + i, z);
  for (int i = gid; i < BAR_U32; i += 32*256) st_cg_u32(bar + i, 0u);
}

// ---------------- prenet (fp16 output) ----------------
__global__ void k_prenet(const float* __restrict__ mels,
                         const float* __restrict__ w1,
                         const float* __restrict__ w2,
                         float* __restrict__ ws) {
  const int t = blockIdx.x >> 4;
  const int b = blockIdx.x & 15;
  const int j = threadIdx.x;
  __shared__ float s_in[NMEL];
  __shared__ float s_x1[PREN];
  if (j < NMEL) s_in[j] = (t == 0) ? 0.0f : mels[(b*TD + (t-1))*NMEL + j];
  __syncthreads();
  float a1 = 0.0f;
  #pragma unroll 8
  for (int k = 0; k < NMEL; ++k) a1 += s_in[k] * w1[j*NMEL + k];
  s_x1[j] = fmaxf(a1, 0.0f);
  __syncthreads();
  float a2 = 0.0f;
  #pragma unroll 8
  for (int k = 0; k < PREN; ++k) a2 += s_x1[k] * w2[j*PREN + k];
  ((_Float16*)(ws + OFF_X2H))[((size_t)t*NB + b)*256 + j] = (_Float16)fmaxf(a2, 0.0f);
}

// ---------------- processed encoder ----------------
__global__ void k_procenc(const float* __restrict__ enc,
                          const float* __restrict__ w,
                          float* __restrict__ pe) {
  const int bt = blockIdx.x;
  const int a = threadIdx.x;
  __shared__ float s_e[EE];
  for (int k = a; k < EE; k += 128) s_e[k] = enc[bt*EE + k];
  __syncthreads();
  float acc = 0.0f;
  #pragma unroll 8
  for (int k = 0; k < EE; ++k) acc += s_e[k] * w[a*EE + k];
  pe[bt*ATT + a] = acc;
}

// ---------------- main decoder loop ----------------
__global__ void __launch_bounds__(512, 1) k_main(
    const float* __restrict__ enc,
    const float* __restrict__ lstm_proj_w,
    const float* __restrict__ loc_conv_w,
    const float* __restrict__ loc_conv_b,
    const float* __restrict__ loc_dense_w,
    const float* __restrict__ loc_dense_b,
    const float* __restrict__ e_w,
    const float* __restrict__ e_b,
    const float* __restrict__ w_ih0,
    const float* __restrict__ b_ih0,
    const float* __restrict__ b_hh0,
    const float* __restrict__ w_ih1,
    const float* __restrict__ b_ih1,
    const float* __restrict__ b_hh1,
    const float* __restrict__ proj_w,
    const float* __restrict__ proj_b,
    const float* __restrict__ stop_w,
    const float* __restrict__ stop_b,
    const int*   __restrict__ text_len,
    float* __restrict__ ws,
    float* __restrict__ out) {
  const int bid = blockIdx.x;
  const int tid = threadIdx.x;

  const unsigned* x2h = (const unsigned*)(ws + OFF_X2H);
  float* pe  = ws + OFF_PE;
  float* en  = ws + OFF_EN;
  unsigned* cth = (unsigned*)(ws + OFF_CTH);
  unsigned* h1h = (unsigned*)(ws + OFF_H1H);
  f4* h2_rec = (f4*)(ws + OFF_H2R);
  f4* qv_rec = (f4*)(ws + OFF_QVR);
  unsigned* bar = (unsigned*)(ws + OFF_BAR);

  __shared__ __align__(16) float s_ldw[NLOC*ATT];   // loc_dense_w^T [c][a] f32
  __shared__ float s_awcf[TE];                      // local cumulative attn
  __shared__ float s_loc[16*33];
  __shared__ float s_red[16];
  __shared__ float s_aw[256];
  __shared__ float s_qtmp[8];
  __shared__ float s_ctmp[32];
  __shared__ __align__(16) float s_q[ATT];
  __shared__ __align__(16) float s_dec[HH+EE];      // [h2 f32 | ctx f32]
  __shared__ float s_b0[12], s_b1[12];
  extern __shared__ __align__(16) unsigned dynlds_u[];
  unsigned* lw0x = dynlds_u;                 // [12][128] u32
  unsigned* lw0c = lw0x + LW0X_U32;          // [12][256] u32
  unsigned* lw1  = lw0c + LW0C_U32;          // [12][512] u32

  const int b_grp = bid & 15;
  const int sub   = bid >> 4;
  const int h0    = bid * 4;

  // ---- one-time staging ----
  for (int i = tid; i < NLOC*ATT; i += 512) {
    int c = i >> 7, a = i & 127;
    s_ldw[i] = loc_dense_w[a*NLOC + c];
  }
  if (tid < 12) {
    int g = tid >> 2, h = tid & 3;
    int gr = (g == 0 ? 0 : (g == 1 ? 2048 : 3072)) + h0 + h;
    s_b0[tid] = b_ih0[gr] + b_hh0[gr];
    s_b1[tid] = b_ih1[gr] + b_hh1[gr];
  }
  for (int i = tid; i < LW0X_U32; i += 512) {
    int r = i >> 7, c = i & 127;
    int g = r >> 2, h = r & 3;
    int grow = (g == 0 ? 0 : (g == 1 ? 2048 : 3072)) + h0 + h;
    const float* wr = w_ih0 + (size_t)grow*768;
    lw0x[i] = pkh(wr[2*c], wr[2*c+1]);
  }
  for (int i = tid; i < LW0C_U32; i += 512) {
    int r = i >> 8, c = i & 255;
    int g = r >> 2, h = r & 3;
    int grow = (g == 0 ? 0 : (g == 1 ? 2048 : 3072)) + h0 + h;
    const float* wr = w_ih0 + (size_t)grow*768 + 256;
    lw0c[i] = pkh(wr[2*c], wr[2*c+1]);
  }
  for (int i = tid; i < LW1_U32; i += 512) {
    int r = i >> 9, c = i & 511;
    int g = r >> 2, h = r & 3;
    int grow = (g == 0 ? 0 : (g == 1 ? 2048 : 3072)) + h0 + h;
    const float* wr = w_ih1 + (size_t)grow*1024;
    lw1[i] = pkh(wr[2*c], wr[2*c+1]);
  }
  if (tid < 256) s_awcf[tid] = 0.0f;

  const int   lenb = text_len[b_grp];
  const float eb0  = e_b[0];
  // P1 invariants
  const int tl = tid >> 5;
  const int j  = tid & 31;
  float lcw_r[KWW];
  #pragma unroll
  for (int k = 0; k < KWW; ++k) lcw_r[k] = loc_conv_w[j*KWW + k];
  const float lcb_r = loc_conv_b[j];
  const f4 db_r = *(const f4*)(loc_dense_b + 4*j);
  const f4 ew_r = *(const f4*)(e_w + 4*j);
  const f4 pe_r = *(const f4*)(pe + (size_t)(b_grp*TE + sub*16 + tl)*ATT + 4*j);
  const f4 ps_r = pe_r + db_r;
  // P2 invariants: enc fragment in registers
  const int e4i = tid >> 6;
  const int ts  = tid & 63;
  f4 encr[4];
  {
    const f4* enc4 = (const f4*)(enc + (size_t)b_grp*TE*EE);
    #pragma unroll
    for (int i = 0; i < 4; ++i)
      encr[i] = enc4[(size_t)(ts + 64*i)*(EE/4) + sub*8 + e4i];
  }
  // P3/P4 mapping
  const int pb = tid >> 5;
  const int kc = tid & 31;
  __syncthreads();

  unsigned eg = 0, el = 0;

  for (int t = 0; t < TD; ++t) {
    const unsigned tg = (unsigned)(t + 1);
    // ===== P1a: conv from s_awcf + loc_dense pre-term (all-LDS) =====
    f4 pre;
    {
      float cv = lcb_r;
      const int pos = sub*16 + tl;
      #pragma unroll
      for (int k = 0; k < KWW; ++k) {
        const int g = pos - PADW + k;
        const float av = (g >= 0 && g < TE) ? s_awcf[g] : 0.0f;
        cv += av * lcw_r[k];
      }
      s_loc[tl*33 + j] = cv;
      __syncthreads();
      f4 d4 = (f4){0.f, 0.f, 0.f, 0.f};
      #pragma unroll 8
      for (int c = 0; c < NLOC; ++c) {
        const float lv = s_loc[tl*33 + c];
        const f4 w4 = ((const f4*)s_ldw)[c*32 + j];
        d4.x += lv*w4.x; d4.y += lv*w4.y; d4.z += lv*w4.z; d4.w += lv*w4.w;
      }
      pre = ps_r + d4;
    }
    // ===== P1b: poll qv recs (tag==t), energies, en store =====
    {
      if (tid < 32) {
        const int src = tid >> 1, r = tid & 1;
        const f4* qp = qv_rec + (b_grp*16 + src)*2 + r;
        f4 v;
        do { v = ld_cg_f4(qp); } while (__float_as_uint(v.z) != (unsigned)t);
        const unsigned u0 = __float_as_uint(v.x), u1 = __float_as_uint(v.y);
        const int base = src*8 + r*4;
        s_q[base+0] = hlo(u0); s_q[base+1] = hhi(u0);
        s_q[base+2] = hlo(u1); s_q[base+3] = hhi(u1);
      }
      __syncthreads();
      const f4 q4 = *(const f4*)(s_q + 4*j);
      float acc = tanhf(pre.x+q4.x)*ew_r.x + tanhf(pre.y+q4.y)*ew_r.y
                + tanhf(pre.z+q4.z)*ew_r.z + tanhf(pre.w+q4.w)*ew_r.w;
      acc = red32(acc);
      if (j == 0) {
        float evv = acc + eb0;
        const int tt = sub*16 + tl;
        if (tt >= lenb) evv = -1e9f;
        st_cg_f32(en + b_grp*TE + tt, evv);
      }
    }
    l_arrive(bar, ++el);
    // ===== mel/stop shadow for t-1 (s_dec intact from prev P5) =====
    if (t > 0) {
      const int ol = tid >> 5, kq = tid & 31;
      if (ol < 6) {
        const int m = sub*6 + ol;
        if (m < 81) {
          const float* wrow = (m < NMEL) ? (proj_w + (size_t)m*(HH+EE)) : stop_w;
          const f4* w4 = (const f4*)wrow;
          const f4* s4 = (const f4*)s_dec;
          float a2 = 0.0f;
          #pragma unroll
          for (int i = 0; i < 12; ++i) a2 += dot4(s4[kq + 32*i], w4[kq + 32*i]);
          a2 = red32(a2);
          if (kq == 0) {
            if (m < NMEL) out[(b_grp*TD + (t-1))*NMEL + m] = a2 + proj_b[m];
            else          out[NB*TD*NMEL + b_grp*TD + (t-1)] = a2 + stop_b[0];
          }
        }
      }
    }
    l_wait(bar, el, b_grp);
    // ===== P2: softmax + local awc + ctx (fp16 store) =====
    {
      float evv = 0.f, p = 0.f;
      if (tid < 256) {
        evv = ld_cg_f32(en + b_grp*TE + tid);
        float m = evv;
        #pragma unroll
        for (int d = 32; d > 0; d >>= 1) m = fmaxf(m, __shfl_xor(m, d));
        if ((tid & 63) == 0) s_red[tid >> 6] = m;
      }
      __syncthreads();
      const float mx = fmaxf(fmaxf(s_red[0], s_red[1]), fmaxf(s_red[2], s_red[3]));
      if (tid < 256) {
        p = expf(evv - mx);
        float sm = p;
        #pragma unroll
        for (int d = 32; d > 0; d >>= 1) sm += __shfl_xor(sm, d);
        if ((tid & 63) == 0) s_red[8 + (tid >> 6)] = sm;
      }
      __syncthreads();
      const float inv = 1.0f / (s_red[8] + s_red[9] + s_red[10] + s_red[11]);
      if (tid < 256) {
        const float aw = p * inv;
        s_aw[tid] = aw;
        s_awcf[tid] += aw;
      }
      __syncthreads();
      f4 a4 = (f4){0.f, 0.f, 0.f, 0.f};
      #pragma unroll
      for (int i = 0; i < 4; ++i) {
        const float awv = s_aw[ts + 64*i];
        a4.x += awv*encr[i].x; a4.y += awv*encr[i].y;
        a4.z += awv*encr[i].z; a4.w += awv*encr[i].w;
      }
      a4.x = red64(a4.x); a4.y = red64(a4.y); a4.z = red64(a4.z); a4.w = red64(a4.w);
      if (ts == 0) {
        s_ctmp[e4i*4+0] = a4.x; s_ctmp[e4i*4+1] = a4.y;
        s_ctmp[e4i*4+2] = a4.z; s_ctmp[e4i*4+3] = a4.w;
      }
      __syncthreads();
      if (tid < 4) {
        u32x4 w;
        w.x = pkh(s_ctmp[8*tid+0], s_ctmp[8*tid+1]);
        w.y = pkh(s_ctmp[8*tid+2], s_ctmp[8*tid+3]);
        w.z = pkh(s_ctmp[8*tid+4], s_ctmp[8*tid+5]);
        w.w = pkh(s_ctmp[8*tid+6], s_ctmp[8*tid+7]);
        u32x4* dst = (u32x4*)cth + b_grp*64 + sub*4 + tid;
        asm volatile("global_store_dwordx4 %0, %1, off sc0 sc1" :: "v"(dst), "v"(w) : "memory");
      }
    }
    g_arrive(bar, ++eg);
    // ===== P3a: LSTM0 x-part (fp16 dot2, independent of ctx) =====
    float acc[12];
    {
      #pragma unroll
      for (int r = 0; r < 12; ++r) acc[r] = 0.0f;
      const u32x4 xv = ((const u32x4*)x2h)[((size_t)t*NB + pb)*32 + kc];
      #pragma unroll
      for (int r = 0; r < 12; ++r) {
        const u32x4 w = ((const u32x4*)lw0x)[r*32 + kc];
        acc[r] = fdot2(xv.x, w.x, acc[r]); acc[r] = fdot2(xv.y, w.y, acc[r]);
        acc[r] = fdot2(xv.z, w.z, acc[r]); acc[r] = fdot2(xv.w, w.w, acc[r]);
      }
    }
    g_wait(bar, eg);                  // ctx ready
    // ===== P3b: LSTM0 ctx-part + gates -> h1 fp16 =====
    // lane-contiguous column chunks (kc, kc+32): 16B lane-stride, conflict-free
    {
      u32x4 c0, c1;
      const u32x4* cp = (const u32x4*)cth + pb*64 + kc;
      ld2u(c0, c1, cp, cp + 32);
      #pragma unroll
      for (int r = 0; r < 12; ++r) {
        const u32x4 w0 = ((const u32x4*)lw0c)[r*64 + kc];
        const u32x4 w1 = ((const u32x4*)lw0c)[r*64 + kc + 32];
        acc[r] = fdot2(c0.x, w0.x, acc[r]); acc[r] = fdot2(c0.y, w0.y, acc[r]);
        acc[r] = fdot2(c0.z, w0.z, acc[r]); acc[r] = fdot2(c0.w, w0.w, acc[r]);
        acc[r] = fdot2(c1.x, w1.x, acc[r]); acc[r] = fdot2(c1.y, w1.y, acc[r]);
        acc[r] = fdot2(c1.z, w1.z, acc[r]); acc[r] = fdot2(c1.w, w1.w, acc[r]);
      }
      #pragma unroll
      for (int r = 0; r < 12; ++r) acc[r] = red32(acc[r]);
      if (kc == 0) {
        float hv[4];
        #pragma unroll
        for (int h = 0; h < 4; ++h) {
          const float gi = acc[h]   + s_b0[h];
          const float gg = acc[4+h] + s_b0[4+h];
          const float go = acc[8+h] + s_b0[8+h];
          hv[h] = sigmf(go) * tanhf(sigmf(gi) * tanhf(gg));
        }
        u32x2 stv; stv.x = pkh(hv[0], hv[1]); stv.y = pkh(hv[2], hv[3]);
        st_cg_u2((u32x2*)h1h + pb*256 + bid, stv);
      }
    }
    g_arrive(bar, ++eg);
    g_wait(bar, eg);                  // h1 ready
    // ===== P4: LSTM1 (fp16 dot2) -> h2 tagged rec =====
    // lane-contiguous column chunks (kc + 32*i): conflict-free
    {
      #pragma unroll
      for (int r = 0; r < 12; ++r) acc[r] = 0.0f;
      u32x4 v0, v1, v2, v3;
      const u32x4* hp = (const u32x4*)h1h + pb*128 + kc;
      ld4u(v0, v1, v2, v3, hp, hp+32, hp+64, hp+96);
      #pragma unroll
      for (int r = 0; r < 12; ++r) {
        const u32x4* wp = (const u32x4*)lw1 + r*128 + kc;
        const u32x4 w0 = wp[0], w1 = wp[32], w2 = wp[64], w3 = wp[96];
        acc[r] = fdot2(v0.x, w0.x, acc[r]); acc[r] = fdot2(v0.y, w0.y, acc[r]);
        acc[r] = fdot2(v0.z, w0.z, acc[r]); acc[r] = fdot2(v0.w, w0.w, acc[r]);
        acc[r] = fdot2(v1.x, w1.x, acc[r]); acc[r] = fdot2(v1.y, w1.y, acc[r]);
        acc[r] = fdot2(v1.z, w1.z, acc[r]); acc[r] = fdot2(v1.w, w1.w, acc[r]);
        acc[r] = fdot2(v2.x, w2.x, acc[r]); acc[r] = fdot2(v2.y, w2.y, acc[r]);
        acc[r] = fdot2(v2.z, w2.z, acc[r]); acc[r] = fdot2(v2.w, w2.w, acc[r]);
        acc[r] = fdot2(v3.x, w3.x, acc[r]); acc[r] = fdot2(v3.y, w3.y, acc[r]);
        acc[r] = fdot2(v3.z, w3.z, acc[r]); acc[r] = fdot2(v3.w, w3.w, acc[r]);
      }
      #pragma unroll
      for (int r = 0; r < 12; ++r) acc[r] = red32(acc[r]);
      if (kc == 0) {
        float hv[4];
        #pragma unroll
        for (int h = 0; h < 4; ++h) {
          const float gi = acc[h]   + s_b1[h];
          const float gg = acc[4+h] + s_b1[4+h];
          const float go = acc[8+h] + s_b1[8+h];
          hv[h] = sigmf(go) * tanhf(sigmf(gi) * tanhf(gg));
        }
        f4 r;
        r.x = __uint_as_float(pkh(hv[0], hv[1]));
        r.y = __uint_as_float(pkh(hv[2], hv[3]));
        r.z = __uint_as_float(tg); r.w = 0.f;
        st_cg_f4(h2_rec + pb*256 + bid, r);
      }
    }
    // ===== P5: poll h2 recs -> s_dec ; ctx -> s_dec ; q -> qv recs =====
    {
      if (tid < 256) {
        const f4* hp = h2_rec + b_grp*256 + tid;
        f4 v;
        do { v = ld_cg_f4(hp); } while (__float_as_uint(v.z) != tg);
        const unsigned u0 = __float_as_uint(v.x), u1 = __float_as_uint(v.y);
        s_dec[4*tid+0] = hlo(u0); s_dec[4*tid+1] = hhi(u0);
        s_dec[4*tid+2] = hlo(u1); s_dec[4*tid+3] = hhi(u1);
      } else if (tid < 320) {
        const int i = tid - 256;
        const u32x4 cv = ld_cg_u4((const u32x4*)cth + b_grp*64 + i);
        s_dec[HH + 8*i + 0] = hlo(cv.x); s_dec[HH + 8*i + 1] = hhi(cv.x);
        s_dec[HH + 8*i + 2] = hlo(cv.y); s_dec[HH + 8*i + 3] = hhi(cv.y);
        s_dec[HH + 8*i + 4] = hlo(cv.z); s_dec[HH + 8*i + 5] = hhi(cv.z);
        s_dec[HH + 8*i + 6] = hlo(cv.w); s_dec[HH + 8*i + 7] = hhi(cv.w);
      }
      __syncthreads();
      const int row = tid >> 6;
      const int kq  = tid & 63;
      const int a   = sub*8 + row;
      const f4* w4 = (const f4*)(lstm_proj_w + (size_t)a*HH);
      const f4* s4 = (const f4*)s_dec;
      float a2 = 0.0f;
      #pragma unroll
      for (int i = 0; i < 4; ++i) a2 += dot4(s4[kq + 64*i], w4[kq + 64*i]);
      a2 = red64(a2);
      if (kq == 0) s_qtmp[row] = a2;
      __syncthreads();
      if (tid < 2) {
        f4 r;
        r.x = __uint_as_float(pkh(s_qtmp[4*tid+0], s_qtmp[4*tid+1]));
        r.y = __uint_as_float(pkh(s_qtmp[4*tid+2], s_qtmp[4*tid+3]));
        r.z = __uint_as_float(tg); r.w = 0.f;
        st_cg_f4(qv_rec + (b_grp*16 + sub)*2 + tid, r);
      }
    }
  }
  // ===== epilogue: mel/stop for t = TD-1 =====
  __syncthreads();
  {
    const int ol = tid >> 5, kq = tid & 31;
    if (ol < 6) {
      const int m = sub*6 + ol;
      if (m < 81) {
        const float* wrow = (m < NMEL) ? (proj_w + (size_t)m*(HH+EE)) : stop_w;
        const f4* w4 = (const f4*)wrow;
        const f4* s4 = (const f4*)s_dec;
        float a2 = 0.0f;
        #pragma unroll
        for (int i = 0; i < 12; ++i) a2 += dot4(s4[kq + 32*i], w4[kq + 32*i]);
        a2 = red32(a2);
        if (kq == 0) {
          if (m < NMEL) out[(b_grp*TD + (TD-1))*NMEL + m] = a2 + proj_b[m];
          else          out[NB*TD*NMEL + b_grp*TD + (TD-1)] = a2 + stop_b[0];
        }
      }
    }
  }
}

extern "C" void kernel_launch(void* const* d_in, const int* in_sizes, int n_in,
                              void* d_out, int out_size, void* d_ws, size_t ws_size,
                              hipStream_t stream) {
  (void)in_sizes; (void)n_in; (void)out_size; (void)ws_size;
  const float* enc         = (const float*)d_in[0];
  const float* mels        = (const float*)d_in[1];
  const float* enc_proj_w  = (const float*)d_in[2];
  const float* lstm_proj_w = (const float*)d_in[3];
  const float* loc_conv_w  = (const float*)d_in[4];
  const float* loc_conv_b  = (const float*)d_in[5];
  const float* loc_dense_w = (const float*)d_in[6];
  const float* loc_dense_b = (const float*)d_in[7];
  const float* e_w         = (const float*)d_in[8];
  const float* e_b         = (const float*)d_in[9];
  const float* prenet1_w   = (const float*)d_in[10];
  const float* prenet2_w   = (const float*)d_in[11];
  const float* w_ih0       = (const float*)d_in[12];
  const float* b_ih0       = (const float*)d_in[14];
  const float* b_hh0       = (const float*)d_in[15];
  const float* w_ih1       = (const float*)d_in[16];
  const float* b_ih1       = (const float*)d_in[18];
  const float* b_hh1       = (const float*)d_in[19];
  const float* proj_w      = (const float*)d_in[20];
  const float* proj_b      = (const float*)d_in[21];
  const float* stop_w      = (const float*)d_in[22];
  const float* stop_b      = (const float*)d_in[23];
  const int*   text_len    = (const int*)d_in[24];
  float* ws  = (float*)d_ws;
  float* out = (float*)d_out;

  static int attr_set = 0;
  if (!attr_set) {
    hipFuncSetAttribute((const void*)k_main,
                        hipFuncAttributeMaxDynamicSharedMemorySize, DYN_BYTES);
    attr_set = 1;
  }

  k_init<<<dim3(32), dim3(256), 0, stream>>>(ws);
  k_prenet<<<dim3(TD*NB), dim3(256), 0, stream>>>(mels, prenet1_w, prenet2_w, ws);
  k_procenc<<<dim3(NB*TE), dim3(128), 0, stream>>>(enc, enc_proj_w, ws + OFF_PE);

  k_main<<<dim3(256), dim3(512), DYN_BYTES, stream>>>(
      enc, lstm_proj_w, loc_conv_w, loc_conv_b, loc_dense_w, loc_dense_b,
      e_w, e_b, w_ih0, b_ih0, b_hh0, w_ih1, b_ih1, b_hh1,
      proj_w, proj_b, stop_w, stop_b, text_len, ws, out);
}